// Round 13
// baseline (226.842 us; speedup 1.0000x reference)
//
#include <hip/hip_runtime.h>
#include <hip/hip_bf16.h>

#define NROWS   16384
#define IN_DIM  1024
#define ENC_DIM 256
#define KCW     8192
#define NCB     32          // codeword col-blocks of 256

typedef __attribute__((ext_vector_type(8))) short short8v;
typedef __attribute__((ext_vector_type(4))) float f32x4;
typedef unsigned long long u64;
typedef unsigned int u32;

// ---------------------------------------------------------------------------
// helpers
// ---------------------------------------------------------------------------
__device__ __forceinline__ unsigned short f2bf_rne(float x) {
    unsigned u = __float_as_uint(x);
    unsigned r = (u + 0x7fffu + ((u >> 16) & 1u)) >> 16;
    return (unsigned short)r;
}
__device__ __forceinline__ float bf2f(unsigned short h) {
    return __uint_as_float(((unsigned)h) << 16);
}
__device__ __forceinline__ int lex_lt(float d, int i, float D, int I) {
    return (d < D) || (d == D && i < I);
}
__device__ __forceinline__ void t2mrg(u64& b1, u64& b2, u64 c1, u64 c2) {
    u64 hi = (b1 > c1) ? b1 : c1;
    u64 lo2 = (b2 < c2) ? b2 : c2;
    b1 = (b1 < c1) ? b1 : c1;
    b2 = (hi < lo2) ? hi : lo2;
}
__device__ __forceinline__ void gload16(const void* g, void* l) {
    __builtin_amdgcn_global_load_lds(
        (__attribute__((address_space(1))) void*)g,
        (__attribute__((address_space(3))) void*)l, 16, 0, 0);
}

// ---------------------------------------------------------------------------
// prep bodies (weights + codewords; cw split fuses the rownorm reduction)
// ---------------------------------------------------------------------------
template<int K>
__device__ __forceinline__ void tsplit_body(const float* __restrict__ W,
                                            unsigned short* __restrict__ Wt,
                                            int Ncols, int idx) {
    int n = idx / (K / 4), k4 = (idx % (K / 4)) * 4;
    float vx = W[(size_t)(k4 + 0) * Ncols + n];
    float vy = W[(size_t)(k4 + 1) * Ncols + n];
    float vz = W[(size_t)(k4 + 2) * Ncols + n];
    float vw = W[(size_t)(k4 + 3) * Ncols + n];
    ushort4 hi, lo;
    hi.x = f2bf_rne(vx); lo.x = f2bf_rne(vx - bf2f(hi.x));
    hi.y = f2bf_rne(vy); lo.y = f2bf_rne(vy - bf2f(hi.y));
    hi.z = f2bf_rne(vz); lo.z = f2bf_rne(vz - bf2f(hi.z));
    hi.w = f2bf_rne(vw); lo.w = f2bf_rne(vw - bf2f(hi.w));
    const int m = (n & 7) << 4;
    char* rp = (char*)(Wt + (size_t)n * (2 * K));
    int bh = k4 * 2, bl = (K + k4) * 2;
    *(ushort4*)(rp + ((bh & ~127) | ((bh & 127) ^ m))) = hi;
    *(ushort4*)(rp + ((bl & ~127) | ((bl & 127) ^ m))) = lo;
}

__global__ __launch_bounds__(256)
void prep_all(const float* __restrict__ ew1, const float* __restrict__ ew2,
              const float* __restrict__ dw1, const float* __restrict__ dw2,
              const float* __restrict__ cw,
              unsigned short* __restrict__ w1ts, unsigned short* __restrict__ ew2t,
              unsigned short* __restrict__ dw1t, unsigned short* __restrict__ dw2t,
              unsigned short* __restrict__ Be,   float* __restrict__ c2) {
    int idx = blockIdx.x * 256 + threadIdx.x;
    if (idx < 65536)        { tsplit_body<1024>(ew1, w1ts, 256, idx); }
    else if (idx < 81920)   { tsplit_body<256>(ew2, ew2t, 256, idx - 65536); }
    else if (idx < 98304)   { tsplit_body<256>(dw1, dw1t, 256, idx - 81920); }
    else if (idx < 163840)  { tsplit_body<256>(dw2, dw2t, 1024, idx - 98304); }
    else if (idx < 688128) {
        // cw split + fused rownorm (64 aligned lanes per row; same shfl tree
        // as the old rownorm_body -> bit-identical c2)
        int e = idx - 163840;
        int row = e >> 6, kq = (e & 63) * 4;
        float4 v = ((const float4*)cw)[e];
        ushort4 hi, lo;
        hi.x = f2bf_rne(v.x); lo.x = f2bf_rne(v.x - bf2f(hi.x));
        hi.y = f2bf_rne(v.y); lo.y = f2bf_rne(v.y - bf2f(hi.y));
        hi.z = f2bf_rne(v.z); lo.z = f2bf_rne(v.z - bf2f(hi.z));
        hi.w = f2bf_rne(v.w); lo.w = f2bf_rne(v.w - bf2f(hi.w));
        const int m = (row & 7) << 4;
        char* rowp = (char*)(Be + (size_t)row * 512);
        int bh = kq * 2, bl = (256 + kq) * 2;
        *(ushort4*)(rowp + ((bh & ~127) | ((bh & 127) ^ m))) = hi;
        *(ushort4*)(rowp + ((bl & ~127) | ((bl & 127) ^ m))) = lo;
        float s = (v.x * v.x + v.y * v.y) + (v.z * v.z + v.w * v.w);
#pragma unroll
        for (int off = 1; off < 64; off <<= 1) s += __shfl_xor(s, off);
        if ((threadIdx.x & 63) == 0) c2[row] = s;
    }
}

// ---------------------------------------------------------------------------
// 512-thread (8-wave) split-bf16 MFMA GEMM body, LDS pool passed in
// (As[128][64] at +0, Bs[128][64] at +16384; 32 KB total).
// EPI: 1 = relu, C fp32 + Cs hi;  2 = relu, Cs hi+lo;  3 = no relu, C only.
// ---------------------------------------------------------------------------
struct MMP {
    const unsigned short* A;
    const unsigned short* Bt;
    const float* bias;
    float* C;
    unsigned short* Cs;
    int N, ars, brs, crs, KQ, EPI, gx;
};

__device__ void mm_device512(const MMP p, int bx, int by, int tid, char* lds) {
    unsigned short (*As)[64] = (unsigned short(*)[64])lds;
    unsigned short (*Bs)[64] = (unsigned short(*)[64])(lds + 16384);
    const int lane = tid & 63;
    const int wid = tid >> 6;
    const int wr = wid >> 2, wc = wid & 3;
    const int brow = by * 128;
    const int bcol = bx * 128;
    const int K = p.KQ * 64;

    f32x4 acc[4][2] = {};

    const int fr = tid >> 3;
    const int fk = (tid & 7) * 8;
    const int swz = (lane & 7) << 4;
    const int arow = wr * 64 + (lane & 15);
    const int brw  = wc * 32 + (lane & 15);
    const int klane = (lane >> 4) * 16;

    bool first = true;
#pragma unroll
    for (int term = 0; term < 3; ++term) {
        const int kaT = (term == 2) ? K : 0;
        const int kbT = (term == 1) ? K : 0;
        for (int kq = 0; kq < p.KQ; ++kq) {
            if (!first) __syncthreads();
            first = false;
            const int ka0 = kaT + kq * 64;
            const int kb0 = kbT + kq * 64;
#pragma unroll
            for (int l = 0; l < 2; ++l) {
                gload16(p.A  + (size_t)(brow + l * 64 + fr) * p.ars + ka0 + fk,
                        (char*)&As[0][0] + l * 8192 + tid * 16);
                gload16(p.Bt + (size_t)(bcol + l * 64 + fr) * p.brs + kb0 + fk,
                        (char*)&Bs[0][0] + l * 8192 + tid * 16);
            }
            __syncthreads();
#pragma unroll
            for (int kk = 0; kk < 2; ++kk) {
                const int kb = (kk * 64 + klane) ^ swz;
                short8v af[4], bfv[2];
#pragma unroll
                for (int mi = 0; mi < 4; mi++)
                    af[mi] = *(const short8v*)((const char*)&As[arow + mi * 16][0] + kb);
#pragma unroll
                for (int ni = 0; ni < 2; ni++)
                    bfv[ni] = *(const short8v*)((const char*)&Bs[brw + ni * 16][0] + kb);
#pragma unroll
                for (int mi = 0; mi < 4; mi++)
#pragma unroll
                    for (int ni = 0; ni < 2; ni++)
                        acc[mi][ni] = __builtin_amdgcn_mfma_f32_16x16x32_bf16(
                            af[mi], bfv[ni], acc[mi][ni], 0, 0, 0);
            }
        }
    }

#pragma unroll
    for (int mi = 0; mi < 4; mi++) {
#pragma unroll
        for (int q = 0; q < 4; q++) {
            int row = brow + wr * 64 + mi * 16 + (lane >> 4) * 4 + q;
            const int m = (row & 7) << 4;
            char* rp = (char*)(p.Cs + (size_t)row * p.crs);
#pragma unroll
            for (int ni = 0; ni < 2; ni++) {
                int col = bcol + wc * 32 + ni * 16 + (lane & 15);
                float v = acc[mi][ni][q] + p.bias[col];
                if (p.EPI != 3) v = fmaxf(v, 0.f);
                if (p.EPI & 1) p.C[(size_t)row * p.N + col] = v;
                if (p.EPI != 3) {
                    unsigned short hi = f2bf_rne(v);
                    int bh = col * 2;
                    *(unsigned short*)(rp + ((bh & ~127) | ((bh & 127) ^ m))) = hi;
                    if (p.EPI == 2) {
                        unsigned short lo = f2bf_rne(v - bf2f(hi));
                        int bl = (256 + col) * 2;
                        *(unsigned short*)(rp + ((bl & ~127) | ((bl & 127) ^ m))) = lo;
                    }
                }
            }
        }
    }
}

__global__ __launch_bounds__(512)
void mm_one(MMP p) {
    __shared__ __align__(16) char pool[32768];
    mm_device512(p, blockIdx.x % p.gx, blockIdx.x / p.gx, threadIdx.x, pool);
}

// ---------------------------------------------------------------------------
// enc1 (unchanged from round 12): single pass over x, 3 terms interleaved.
// ---------------------------------------------------------------------------
__global__ __launch_bounds__(512)
void enc1_fused(const float* __restrict__ x,
                const unsigned short* __restrict__ w1ts,
                const float* __restrict__ bias,
                unsigned short* __restrict__ Hs) {
    __shared__ __align__(16) unsigned short Ah[64][64];
    __shared__ __align__(16) unsigned short Al[64][64];
    __shared__ __align__(16) unsigned short Bh[256][64];
    __shared__ __align__(16) unsigned short Bl[256][64];
    const int tid = threadIdx.x;
    const int lane = tid & 63;
    const int wid = tid >> 6;
    const int wr = wid >> 2, wc = wid & 3;
    const int brow = blockIdx.x * 64;

    f32x4 acc[2][4] = {};

    const int fr = tid >> 3;
    const int fk = (tid & 7) * 8;
    const int swz = (lane & 7) << 4;
    const int arow = wr * 32 + (lane & 15);
    const int brw  = wc * 64 + (lane & 15);
    const int klane = (lane >> 4) * 16;
    const int aoff = fr * 128 + ((fk * 2) ^ ((fr & 7) << 4));

    float4 c0, c1, n0, n1;
    {
        const float* xp = x + (size_t)(brow + fr) * 1024 + fk;
        c0 = *(const float4*)xp; c1 = *(const float4*)(xp + 4);
    }

    for (int s = 0; s < 16; ++s) {
        const int k0 = s * 64;
        if (s) __syncthreads();
        {
            float vv[8] = { c0.x, c0.y, c0.z, c0.w, c1.x, c1.y, c1.z, c1.w };
            short8v uh, ul;
#pragma unroll
            for (int i = 0; i < 8; i++) {
                unsigned short h = f2bf_rne(vv[i]);
                uh[i] = (short)h;
                ul[i] = (short)f2bf_rne(vv[i] - bf2f(h));
            }
            *(short8v*)((char*)&Ah[0][0] + aoff) = uh;
            *(short8v*)((char*)&Al[0][0] + aoff) = ul;
        }
#pragma unroll
        for (int l = 0; l < 4; ++l) {
            gload16(w1ts + (size_t)(l * 64 + fr) * 2048 + k0 + fk,
                    (char*)&Bh[0][0] + l * 8192 + tid * 16);
            gload16(w1ts + (size_t)(l * 64 + fr) * 2048 + 1024 + k0 + fk,
                    (char*)&Bl[0][0] + l * 8192 + tid * 16);
        }
        if (s + 1 < 16) {
            const float* xp = x + (size_t)(brow + fr) * 1024 + k0 + 64 + fk;
            n0 = *(const float4*)xp; n1 = *(const float4*)(xp + 4);
        }
        __syncthreads();
#pragma unroll
        for (int kk = 0; kk < 2; ++kk) {
            const int kb = (kk * 64 + klane) ^ swz;
            short8v ah[2], al[2], bh[4], bl[4];
#pragma unroll
            for (int mi = 0; mi < 2; mi++) {
                ah[mi] = *(const short8v*)((const char*)&Ah[arow + mi * 16][0] + kb);
                al[mi] = *(const short8v*)((const char*)&Al[arow + mi * 16][0] + kb);
            }
#pragma unroll
            for (int ni = 0; ni < 4; ni++) {
                bh[ni] = *(const short8v*)((const char*)&Bh[brw + ni * 16][0] + kb);
                bl[ni] = *(const short8v*)((const char*)&Bl[brw + ni * 16][0] + kb);
            }
#pragma unroll
            for (int mi = 0; mi < 2; mi++)
#pragma unroll
                for (int ni = 0; ni < 4; ni++) {
                    acc[mi][ni] = __builtin_amdgcn_mfma_f32_16x16x32_bf16(
                        ah[mi], bh[ni], acc[mi][ni], 0, 0, 0);
                    acc[mi][ni] = __builtin_amdgcn_mfma_f32_16x16x32_bf16(
                        ah[mi], bl[ni], acc[mi][ni], 0, 0, 0);
                    acc[mi][ni] = __builtin_amdgcn_mfma_f32_16x16x32_bf16(
                        al[mi], bh[ni], acc[mi][ni], 0, 0, 0);
                }
        }
        c0 = n0; c1 = n1;
    }

#pragma unroll
    for (int mi = 0; mi < 2; mi++) {
#pragma unroll
        for (int q = 0; q < 4; q++) {
            int row = brow + wr * 32 + mi * 16 + (lane >> 4) * 4 + q;
            const int m = (row & 7) << 4;
            char* rp = (char*)(Hs + (size_t)row * 512);
#pragma unroll
            for (int ni = 0; ni < 4; ni++) {
                int col = wc * 64 + ni * 16 + (lane & 15);
                float v = fmaxf(acc[mi][ni][q] + bias[col], 0.f);
                unsigned short hi = f2bf_rne(v);
                unsigned short lo = f2bf_rne(v - bf2f(hi));
                int bh_ = col * 2, bl_ = (256 + col) * 2;
                *(unsigned short*)(rp + ((bh_ & ~127) | ((bh_ & 127) ^ m))) = hi;
                *(unsigned short*)(rp + ((bl_ & ~127) | ((bl_ & 127) ^ m))) = lo;
            }
        }
    }
}

// ---------------------------------------------------------------------------
// VQ MFMA kernel, TRIPLE-BUFFERED counted-vmcnt pipeline (+dec1 blocks):
// per step: stage(s+2) at top (WAR-safe: that buffer's reads ended at s-1,
// behind a barrier), compute buf[s%3], then vmcnt(6) [waits only stage(s+1),
// issued a full step earlier] + raw s_barrier. One barrier/step, loads never
// drained to 0 mid-loop. Static LDS 151552 B -> 1 block/CU, 8 waves.
// Math identical to round 12 -> absmax must stay bit-identical (race canary).
// ---------------------------------------------------------------------------
__global__ __launch_bounds__(512)
void vq_mfma(const unsigned short* __restrict__ Ae,
             const unsigned short* __restrict__ Be,
             const float* __restrict__ c2,
             ulonglong2* __restrict__ part,
             MMP pd, int nvq) {
    __shared__ __align__(16) char pool[151552];
    if ((int)blockIdx.x >= nvq) {
        int b = blockIdx.x - nvq;
        mm_device512(pd, b % pd.gx, b / pd.gx, threadIdx.x, pool);
        return;
    }
    const int tid  = threadIdx.x;
    const int lane = tid & 63;
    const int wid  = tid >> 6;
    const int wr   = wid >> 2;
    const int wc   = wid & 3;
    const int bid  = blockIdx.x;
    const int brow = (bid >> 5) * 128;
    const int bcol = (bid & 31) * 256;

    u32* s1 = (u32*)(pool + 147456);   // [128][4]
    u32* s2 = (u32*)(pool + 149504);   // [128][4]

    const int fr = tid >> 3;
    const int fk = (tid & 7) * 8;
    const int swz   = (lane & 7) << 4;
    const int arow  = wr * 64 + (lane & 15);
    const int brw   = wc * 64 + (lane & 15);
    const int klane = (lane >> 4) * 16;

    auto stage = [&](int s, int buf) {
        char* A = pool + buf * 49152;
        char* B = A + 16384;
        const int k0 = s * 64;
#pragma unroll
        for (int l = 0; l < 2; ++l)
            gload16(Ae + (size_t)(brow + l * 64 + fr) * 256 + k0 + fk,
                    A + l * 8192 + tid * 16);
#pragma unroll
        for (int l = 0; l < 4; ++l)
            gload16(Be + (size_t)(bcol + l * 64 + fr) * 512 + k0 + fk,
                    B + l * 8192 + tid * 16);
    };

    f32x4 acc[4][4] = {};

    stage(0, 0);
    stage(1, 1);
    asm volatile("s_waitcnt vmcnt(6)" ::: "memory");
    __builtin_amdgcn_s_barrier();

#pragma unroll
    for (int s = 0; s < 4; ++s) {
        const int buf = s % 3;
        if (s + 2 < 4) stage(s + 2, (s + 2) % 3);
        const char* A = pool + buf * 49152;
        const char* B = A + 16384;
        __builtin_amdgcn_s_setprio(1);
#pragma unroll
        for (int kk = 0; kk < 2; ++kk) {
            const int kb = (kk * 64 + klane) ^ swz;
            short8v af[4], bfv[4];
#pragma unroll
            for (int mi = 0; mi < 4; mi++)
                af[mi] = *(const short8v*)(A + (arow + mi * 16) * 128 + kb);
#pragma unroll
            for (int ni = 0; ni < 4; ni++)
                bfv[ni] = *(const short8v*)(B + (brw + ni * 16) * 128 + kb);
#pragma unroll
            for (int mi = 0; mi < 4; mi++)
#pragma unroll
                for (int ni = 0; ni < 4; ni++)
                    acc[mi][ni] = __builtin_amdgcn_mfma_f32_16x16x32_bf16(
                        bfv[ni], af[mi], acc[mi][ni], 0, 0, 0);
        }
        __builtin_amdgcn_s_setprio(0);
        if (s == 0 || s == 1) {
            asm volatile("s_waitcnt vmcnt(6)" ::: "memory");
            __builtin_amdgcn_s_barrier();
        } else if (s == 2) {
            asm volatile("s_waitcnt vmcnt(0)" ::: "memory");
            __builtin_amdgcn_s_barrier();
        }
    }

    // ---- epilogue: swapped layout, in-register top-2, u32 keys ----
    const int qrow = lane & 15;
    const int cq   = (lane >> 4) * 4;
    float4 c2q[4];
#pragma unroll
    for (int ni = 0; ni < 4; ni++)
        c2q[ni] = *(const float4*)&c2[bcol + wc * 64 + ni * 16 + cq];

#pragma unroll
    for (int mi = 0; mi < 4; mi++) {
        u32 b1 = 0xFFFFFFFFu, b2 = 0xFFFFFFFFu;
#pragma unroll
        for (int ni = 0; ni < 4; ni++) {
            const float* cp = (const float*)&c2q[ni];
#pragma unroll
            for (int r = 0; r < 4; r++) {
                float dk = fmaf(-2.0f, acc[mi][ni][r], cp[r]);
                dk = fmaxf(dk, 0.0f);
                u32 k = (__float_as_uint(dk) & ~255u)
                      | (u32)(wc * 64 + ni * 16 + cq + r);
                u32 mx = max(k, b1);
                b1 = min(k, b1);
                b2 = min(mx, b2);
            }
        }
#pragma unroll
        for (int off = 16; off < 64; off <<= 1) {
            u32 o1 = __shfl_xor(b1, off);
            u32 o2 = __shfl_xor(b2, off);
            u32 mx = max(b1, o1);
            b1 = min(b1, o1);
            b2 = min(min(b2, o2), mx);
        }
        if (lane < 16) {
            int rl = wr * 64 + mi * 16 + qrow;
            s1[rl * 4 + wc] = b1;
            s2[rl * 4 + wc] = b2;
        }
    }
    __syncthreads();
    if (tid < 128) {
        u32 b1 = s1[tid * 4 + 0], b2 = s2[tid * 4 + 0];
#pragma unroll
        for (int w = 1; w < 4; w++) {
            u32 c1 = s1[tid * 4 + w], cc2 = s2[tid * 4 + w];
            u32 mx = max(b1, c1);
            b1 = min(b1, c1);
            b2 = min(min(b2, cc2), mx);
        }
        ulonglong2 pk;
        pk.x = ((u64)b1 << 32) | (u32)(bcol + (b1 & 255u));
        pk.y = ((u64)b2 << 32) | (u32)(bcol + (b2 & 255u));
        part[(size_t)(brow + tid) * NCB + (bid & 31)] = pk;
    }
}

// ---------------------------------------------------------------------------
// combine (8 rows/block, fused outQ + exact rescore) with dec2 blocks FIRST.
// ---------------------------------------------------------------------------
__global__ __launch_bounds__(512)
void combine_dec2(const ulonglong2* __restrict__ part,
                  const float* __restrict__ enc,
                  const float* __restrict__ cw,
                  const float* __restrict__ c2,
                  float* __restrict__ outIdx,
                  float* __restrict__ outDist,
                  int* __restrict__ idx32,
                  float* __restrict__ outQ,
                  MMP pd, int nd2) {
    __shared__ __align__(16) char pool[32768];
    if ((int)blockIdx.x < nd2) {
        mm_device512(pd, blockIdx.x % pd.gx, blockIdx.x / pd.gx, threadIdx.x, pool);
        return;
    }
    const int row  = (blockIdx.x - nd2) * 8 + (threadIdx.x >> 6);
    const int lane = threadIdx.x & 63;

    u64 b1 = ~0ull, b2 = ~0ull;
    if (lane < NCB) {
        ulonglong2 pk = part[(size_t)row * NCB + lane];
        b1 = pk.x; b2 = pk.y;
    }
#pragma unroll
    for (int off = 1; off < 64; off <<= 1) {
        u64 c1 = __shfl_xor(b1, off);
        u64 cc2 = __shfl_xor(b2, off);
        t2mrg(b1, b2, c1, cc2);
    }
    int j1 = (int)(b1 & 0xffffffffu);
    int j2 = (int)(b2 & 0xffffffffu);

    float4 e4 = ((const float4*)(enc + (size_t)row * 256))[lane];
    float4 w1 = ((const float4*)(cw + (size_t)j1 * 256))[lane];
    float4 w2 = ((const float4*)(cw + (size_t)j2 * 256))[lane];
    float s1 = fmaf(e4.x, w1.x, fmaf(e4.y, w1.y, fmaf(e4.z, w1.z, e4.w * w1.w)));
    float s2 = fmaf(e4.x, w2.x, fmaf(e4.y, w2.y, fmaf(e4.z, w2.z, e4.w * w2.w)));
    float sx = (e4.x * e4.x + e4.y * e4.y) + (e4.z * e4.z + e4.w * e4.w);
#pragma unroll
    for (int off = 1; off < 64; off <<= 1) {
        s1 += __shfl_xor(s1, off);
        s2 += __shfl_xor(s2, off);
        sx += __shfl_xor(sx, off);
    }
    float d1 = sqrtf(fmaxf(sx + c2[j1] - 2.0f * s1, 0.f));
    float d2 = sqrtf(fmaxf(sx + c2[j2] - 2.0f * s2, 0.f));
    float bd; int bi;
    if (lex_lt(d1, j1, d2, j2)) { bd = d1; bi = j1; }
    else                        { bd = d2; bi = j2; }
    float4 wq = (bi == j1) ? w1 : w2;
    ((float4*)(outQ + (size_t)row * ENC_DIM))[lane] = wq;
    if (lane == 0) {
        outIdx[row]  = (float)bi;
        outDist[row] = bd;
        idx32[row]   = bi;
    }
}

// ---------------------------------------------------------------------------
// Gather reconstructed rows (outRec only). 4 rows per block.
// ---------------------------------------------------------------------------
__global__ void gather_rec(const int* __restrict__ idx32,
                           const float* __restrict__ rec_all,
                           float* __restrict__ outRec) {
    int row = blockIdx.x * 4 + (threadIdx.x >> 6);
    int lane = threadIdx.x & 63;
    int j = idx32[row];
    const float4* src = (const float4*)(rec_all + (size_t)j * IN_DIM);
    float4* dst = (float4*)(outRec + (size_t)row * IN_DIM);
#pragma unroll
    for (int i = 0; i < 4; i++) dst[lane + 64 * i] = src[lane + 64 * i];
}

extern "C" void kernel_launch(void* const* d_in, const int* in_sizes, int n_in,
                              void* d_out, int out_size, void* d_ws, size_t ws_size,
                              hipStream_t stream) {
    const float* x   = (const float*)d_in[0];
    const float* ew1 = (const float*)d_in[1];
    const float* eb1 = (const float*)d_in[2];
    const float* ew2 = (const float*)d_in[3];
    const float* eb2 = (const float*)d_in[4];
    const float* cw  = (const float*)d_in[5];
    const float* dw1 = (const float*)d_in[6];
    const float* db1 = (const float*)d_in[7];
    const float* dw2 = (const float*)d_in[8];
    const float* db2 = (const float*)d_in[9];
    float* out = (float*)d_out;
    float* ws  = (float*)d_ws;

    float* outIdx  = out;
    float* outDist = out + NROWS;
    float* outRec  = out + 2 * NROWS;
    float* outQ    = out + 2 * NROWS + (size_t)NROWS * IN_DIM;

    // layout (~21.7M floats). liveness: Hs (enc1->enc2) aliased by part
    // (vq+) and rec_all head (combine_dec2+); serial-launch ordered.
    float*          enc     = ws;                               // [0, 4.19M)
    unsigned short* Ae      = (unsigned short*)(ws + 4194304);  // [., 6.29M)
    unsigned short* Gs      = (unsigned short*)(ws + 6291456);  // [., 8.39M)
    unsigned short* Hs      = (unsigned short*)(ws + 8388608);  // [., 12.58M)
    ulonglong2*     part    = (ulonglong2*)(ws + 8388608);      // [., 10.49M)
    float*          rec_all = ws + 10485760;                    // [., 18.87M)
    unsigned short* Be      = (unsigned short*)(ws + 18874368); // [., 20.97M)
    unsigned short* w1ts    = (unsigned short*)(ws + 20971520); // 1 MB
    unsigned short* ew2t    = (unsigned short*)(ws + 21233664);
    unsigned short* dw1t    = (unsigned short*)(ws + 21299200);
    unsigned short* dw2t    = (unsigned short*)(ws + 21364736);
    float*          c2      = ws + 21626880;
    int*            idx32   = (int*)(ws + 21635072);

    MMP p_enc2 = { Hs, ew2t, eb2, enc, Ae, 256, 512, 512, 256, 4, 1, 2 };
    MMP p_dec1 = { Be, dw1t, db1, nullptr, Gs, 256, 512, 512, 512, 4, 2, 2 };
    MMP p_dec2 = { Gs, dw2t, db2, rec_all, nullptr, 1024, 512, 512, 0, 4, 3, 8 };

    prep_all<<<2688, 256, 0, stream>>>(ew1, ew2, dw1, dw2, cw,
                                       w1ts, ew2t, dw1t, dw2t, Be, c2);
    enc1_fused<<<256, 512, 0, stream>>>(x, w1ts, eb1, Hs);
    mm_one<<<256, 512, 0, stream>>>(p_enc2);
    vq_mfma<<<4096 + 128, 512, 0, stream>>>(Ae, Be, c2, part, p_dec1, 4096);
    combine_dec2<<<512 + 2048, 512, 0, stream>>>(part, enc, cw, c2,
                                                 outIdx, outDist, idx32, outQ,
                                                 p_dec2, 512);
    gather_rec<<<NROWS / 4, 256, 0, stream>>>(idx32, rec_all, outRec);
}